// Round 4
// baseline (341.087 us; speedup 1.0000x reference)
//
#include <hip/hip_runtime.h>
#include <math.h>

// Problem constants
#define N_IMG 128
#define IC 8
#define IH 128
#define IW 128
#define OC 64
#define OH 126
#define OW 126
#define NG 16
#define CPG 4          // channels per group
#define PH 31
#define PW 31
#define GN_EPS 1e-5f

// conv4: compute 4 consecutive output columns x 4 channels of the 3x3 conv.
// Used only for the stats-only edge strips (cols 124-125, rows 124-125).
// acc[j][ch] must be pre-initialized (bias). Weights in LDS laid out
// [ic][kh][kw][ch] (12 floats per (ic,kh) -> 3x ds_read_b128, broadcast).
// NOTE: weights/bias are pre-multiplied by sgn(gn_w*scale) per channel; the
// sign is restored in the stats reduction (s_ch) and the pool-max fold.
// If edge==true, columns ow+4..ow+5 are not loaded (outputs j=2,3 garbage,
// caller must mask).
__device__ __forceinline__ void conv4(const float* __restrict__ xb,
                                      const float* wlds_,
                                      int oh, int ow, bool edge,
                                      float acc[4][CPG]) {
#pragma unroll 1
    for (int ic = 0; ic < IC; ic++) {
        const float* xr = xb + ic * (IH * IW) + oh * IW + ow;
#pragma unroll
        for (int kh = 0; kh < 3; kh++) {
            const float* xrr = xr + kh * IW;
            float4 f4 = *(const float4*)xrr;           // cols ow..ow+3 (16B aligned)
            float v0 = f4.x, v1 = f4.y, v2 = f4.z, v3 = f4.w;
            float v4 = 0.f, v5 = 0.f;
            if (!edge) {
                float2 f2 = *(const float2*)(xrr + 4); // cols ow+4..ow+5
                v4 = f2.x; v5 = f2.y;
            }
            const float* wk = wlds_ + (ic * 3 + kh) * 12;
            float wr[12];
#pragma unroll
            for (int t = 0; t < 12; t++) wr[t] = wk[t];
#pragma unroll
            for (int ch = 0; ch < CPG; ch++) {
                float w0 = wr[0 * 4 + ch];
                float w1 = wr[1 * 4 + ch];
                float w2 = wr[2 * 4 + ch];
                acc[0][ch] = fmaf(v0, w0, fmaf(v1, w1, fmaf(v2, w2, acc[0][ch])));
                acc[1][ch] = fmaf(v1, w0, fmaf(v2, w1, fmaf(v3, w2, acc[1][ch])));
                acc[2][ch] = fmaf(v2, w0, fmaf(v3, w1, fmaf(v4, w2, acc[2][ch])));
                acc[3][ch] = fmaf(v3, w0, fmaf(v4, w1, fmaf(v5, w2, acc[3][ch])));
            }
        }
    }
}

// One block per (n, group), XCD-swizzled so each XCD owns contiguous images
// (all 16 group-blocks of an image co-resident on one XCD -> x fetched ~once
// per image from HBM; verified: FETCH_SIZE 850MB -> 93MB -> 40MB L3-warm).
// Single conv pass. Per pool cell: ONE 4-output-row register block
//  - 6 x-rows loaded once per ic; each ic's 36 LDS weights read once
//  - ic loop at unroll 2: iteration i+1's 12 x-loads + 9 ds_reads issue under
//    iteration i's 1728-cycle FMA run (cross-ic software pipeline; unroll 1
//    measured VALUBusy=67% with the stall at each ic's vmcnt lead-in)
//  - weights/bias pre-multiplied by sgn(gn_w*scale): pool extreme is a bare
//    fmaxf; sum/sumsq kept per-channel (4 parallel dependency chains)
// Then out = clamp(rstd*|gn_w*scale|*M + (gn_b - mean*rstd*gn_w)*scale, 0, 1).
// VGPR budget: acc 64 + 2x xv 72 + wr 12 + pm/stats ~24 -> ~150; cap 170 via
// __launch_bounds__(256,3). Residency cap is NOT binding (measured 2.3
// waves/SIMD time-avg at a 6-wave cap in round 3), so the 6->3 drop is free.
__launch_bounds__(256, 3)
__global__ void fused_conv_gn_pool_kernel(const float* __restrict__ x,
                                          const float* __restrict__ conv_w,
                                          const float* __restrict__ conv_b,
                                          const float* __restrict__ gn_w,
                                          const float* __restrict__ gn_b,
                                          const float* __restrict__ scale,
                                          float* __restrict__ out) {
    const int b = blockIdx.x;               // 0..2047 hardware block id
    // XCD-aware swizzle: hw blocks round-robin XCDs by (b % 8); give XCD j
    // the contiguous work range [j*256, (j+1)*256) == images j*16..j*16+15.
    const int wid = ((b & 7) << 8) | (b >> 3);
    const int n = wid >> 4;
    const int g = wid & 15;
    const int tid = threadIdx.x;

    __shared__ float wlds[IC * 3 * 3 * CPG];   // 288 floats, [ic][kh][kw][ch], signed
    __shared__ float red[8];                    // 4 waves x {sum, sumsq}
    __shared__ float stats[2];                  // mean, rstd

    for (int t = tid; t < IC * 3 * 3 * CPG; t += 256) {
        int ch = t & 3;
        int r = t >> 2;                        // ic*9 + kh*3 + kw
        int c = g * CPG + ch;
        float sg = (gn_w[c] * scale[c] >= 0.f) ? 1.f : -1.f;
        wlds[t] = conv_w[c * (IC * 9) + r] * sg;
    }
    float biasS[CPG], sgnf[CPG];
#pragma unroll
    for (int ch = 0; ch < CPG; ch++) {
        int c = g * CPG + ch;
        float sg = (gn_w[c] * scale[c] >= 0.f) ? 1.f : -1.f;
        sgnf[ch] = sg;
        biasS[ch] = conv_b[c] * sg;
    }
    __syncthreads();

    const float* xb = x + (size_t)n * (IC * IH * IW);

    float s_ch[CPG];                 // per-channel signed-conv partial sums
    float ss_ch[CPG];                // per-channel sum of squares (4 chains)
#pragma unroll
    for (int ch = 0; ch < CPG; ch++) { s_ch[ch] = 0.f; ss_ch[ch] = 0.f; }
    float pm[4][CPG];                // running extreme per owned pool cell
#pragma unroll
    for (int ci = 0; ci < 4; ci++)
#pragma unroll
        for (int ch = 0; ch < CPG; ch++) pm[ci][ch] = -INFINITY;

    // ---- Main: pool region (conv rows/cols 0..123), one pass ----
#pragma unroll 1
    for (int ci = 0; ci < 4; ci++) {
        int cell = tid + ci * 256;
        if (cell < PH * PW) {
            int ph = cell / PW;
            int pw = cell - ph * PW;
            const int r0 = 4 * ph;             // conv rows r0..r0+3
            const float* xcell = xb + r0 * IW + 4 * pw;

            float acc[4][4][CPG];              // [row][col][ch]
#pragma unroll
            for (int rr = 0; rr < 4; rr++)
#pragma unroll
                for (int j = 0; j < 4; j++)
#pragma unroll
                    for (int ch = 0; ch < CPG; ch++) acc[rr][j][ch] = biasS[ch];

#pragma unroll 2
            for (int ic = 0; ic < IC; ic++) {
                const float* xr = xcell + ic * (IH * IW);
                // 6 x-rows x 6 cols in registers (rows r0..r0+5 <= 125,
                // cols 4pw..4pw+5 <= 125; float4 at 4pw is 16B aligned)
                float xv[6][6];
#pragma unroll
                for (int rr = 0; rr < 6; rr++) {
                    float4 f4 = *(const float4*)(xr + rr * IW);
                    float2 f2 = *(const float2*)(xr + rr * IW + 4);
                    xv[rr][0] = f4.x; xv[rr][1] = f4.y;
                    xv[rr][2] = f4.z; xv[rr][3] = f4.w;
                    xv[rr][4] = f2.x; xv[rr][5] = f2.y;
                }
                const float* wk = wlds + ic * 36;
#pragma unroll
                for (int kh = 0; kh < 3; kh++) {
                    float wr[12];
#pragma unroll
                    for (int t = 0; t < 12; t++) wr[t] = wk[kh * 12 + t];
#pragma unroll
                    for (int ch = 0; ch < CPG; ch++) {
                        float w0 = wr[0 * 4 + ch];
                        float w1 = wr[1 * 4 + ch];
                        float w2 = wr[2 * 4 + ch];
#pragma unroll
                        for (int rr = 0; rr < 4; rr++) {
                            const float* xrow = xv[rr + kh];
#pragma unroll
                            for (int j = 0; j < 4; j++) {
                                acc[rr][j][ch] = fmaf(xrow[j],     w0,
                                                 fmaf(xrow[j + 1], w1,
                                                 fmaf(xrow[j + 2], w2, acc[rr][j][ch])));
                            }
                        }
                    }
                }
            }
            // fold into stats + pool extremes (signed domain)
#pragma unroll
            for (int rr = 0; rr < 4; rr++)
#pragma unroll
                for (int j = 0; j < 4; j++)
#pragma unroll
                    for (int ch = 0; ch < CPG; ch++) {
                        float v = acc[rr][j][ch];
                        s_ch[ch] += v;
                        ss_ch[ch] = fmaf(v, v, ss_ch[ch]);
                        pm[ci][ch] = fmaxf(pm[ci][ch], v);
                    }
        }
    }

    // ---- Edges: conv outputs needed for stats only ----
    if (tid < 124) {
        // right edge: oh=tid, cols 124..125
        float acc[4][CPG];
#pragma unroll
        for (int j = 0; j < 4; j++)
#pragma unroll
            for (int ch = 0; ch < CPG; ch++) acc[j][ch] = biasS[ch];
        conv4(xb, wlds, tid, 124, true, acc);
#pragma unroll
        for (int j = 0; j < 2; j++)
#pragma unroll
            for (int ch = 0; ch < CPG; ch++) {
                float v = acc[j][ch];
                s_ch[ch] += v;
                ss_ch[ch] = fmaf(v, v, ss_ch[ch]);
            }
    } else if (tid >= 128 && tid < 192) {
        // bottom rows: oh in {124,125}, all 126 cols
        int idx = tid - 128;
        int oh = 124 + (idx >> 5);
        int q = idx & 31;
        bool edge = (q == 31);
        float acc[4][CPG];
#pragma unroll
        for (int j = 0; j < 4; j++)
#pragma unroll
            for (int ch = 0; ch < CPG; ch++) acc[j][ch] = biasS[ch];
        conv4(xb, wlds, oh, q * 4, edge, acc);
        int jmax = edge ? 2 : 4;
#pragma unroll
        for (int j = 0; j < 4; j++) {
            if (j < jmax) {
#pragma unroll
                for (int ch = 0; ch < CPG; ch++) {
                    float v = acc[j][ch];
                    s_ch[ch] += v;
                    ss_ch[ch] = fmaf(v, v, ss_ch[ch]);
                }
            }
        }
    }

    // ---- Block reduction for GN stats (restore per-channel sign) ----
    float s = sgnf[0] * s_ch[0] + sgnf[1] * s_ch[1]
            + sgnf[2] * s_ch[2] + sgnf[3] * s_ch[3];
    float ss = ss_ch[0] + ss_ch[1] + ss_ch[2] + ss_ch[3];
#pragma unroll
    for (int off = 32; off > 0; off >>= 1) {
        s  += __shfl_down(s, off, 64);
        ss += __shfl_down(ss, off, 64);
    }
    int wave = tid >> 6;
    if ((tid & 63) == 0) { red[wave] = s; red[4 + wave] = ss; }
    __syncthreads();
    if (tid == 0) {
        float S  = red[0] + red[1] + red[2] + red[3];
        float SS = red[4] + red[5] + red[6] + red[7];
        const float inv_count = 1.f / (float)(CPG * OH * OW);
        float mean = S * inv_count;
        float var = SS * inv_count - mean * mean;
        if (var < 0.f) var = 0.f;
        stats[0] = mean;
        stats[1] = rsqrtf(var + GN_EPS);
    }
    __syncthreads();
    const float mean = stats[0];
    const float rstd = stats[1];

    // Fused affine for the pooled extreme: out = a2*M + b2  (a2 >= 0,
    // M is the signed-domain max, equal to max over window of sgn*v)
    float a2[CPG], b2[CPG];
#pragma unroll
    for (int ch = 0; ch < CPG; ch++) {
        int c = g * CPG + ch;
        float gw = gn_w[c], sc = scale[c];
        a2[ch] = rstd * fabsf(gw * sc);
        b2[ch] = (gn_b[c] - mean * rstd * gw) * sc;
    }

    // ---- Write pooled, clamped output ----
#pragma unroll
    for (int ci = 0; ci < 4; ci++) {
        int cell = tid + ci * 256;
        if (cell < PH * PW) {
            int ph = cell / PW;
            int pw = cell - ph * PW;
#pragma unroll
            for (int ch = 0; ch < CPG; ch++) {
                int c = g * CPG + ch;
                float v = fmaf(a2[ch], pm[ci][ch], b2[ch]);
                v = fminf(fmaxf(v, 0.f), 1.f);
                out[(((size_t)n * OC + c) * PH + ph) * PW + pw] = v;
            }
        }
    }
}

extern "C" void kernel_launch(void* const* d_in, const int* in_sizes, int n_in,
                              void* d_out, int out_size, void* d_ws, size_t ws_size,
                              hipStream_t stream) {
    const float* x      = (const float*)d_in[0];
    const float* conv_w = (const float*)d_in[1];
    const float* conv_b = (const float*)d_in[2];
    const float* gn_w   = (const float*)d_in[3];
    const float* gn_b   = (const float*)d_in[4];
    const float* scale  = (const float*)d_in[5];
    float* out = (float*)d_out;

    dim3 grid(N_IMG * NG);   // one block per (n, group), XCD-swizzled in-kernel
    dim3 block(256);
    hipLaunchKernelGGL(fused_conv_gn_pool_kernel, grid, block, 0, stream,
                       x, conv_w, conv_b, gn_w, gn_b, scale, out);
}

// Round 5
// 328.932 us; speedup vs baseline: 1.0370x; 1.0370x over previous
//
#include <hip/hip_runtime.h>
#include <math.h>

// Problem constants
#define N_IMG 128
#define IC 8
#define IH 128
#define IW 128
#define OC 64
#define OH 126
#define OW 126
#define NG 16
#define CPG 4          // channels per group
#define PH 31
#define PW 31
#define GN_EPS 1e-5f

// edge2: compute 2 consecutive output columns (ow, ow+1) x 4 channels of the
// 3x3 conv for one output row. Stats-only edge work (cols 124-125 / rows
// 124-125). ow must be even (float2 loads are 8B aligned). acc pre-init'd
// with (signed) bias. Weights in LDS [ic][kh][kw][ch], pre-multiplied by
// sgn(gn_w*scale).
__device__ __forceinline__ void edge2(const float* __restrict__ xb,
                                      const float* wlds_,
                                      int oh, int ow,
                                      float acc[2][CPG]) {
#pragma unroll 1
    for (int ic = 0; ic < IC; ic++) {
        const float* xr = xb + ic * (IH * IW) + oh * IW + ow;
        float xv[3][4];
#pragma unroll
        for (int kh = 0; kh < 3; kh++) {
            float2 a = *(const float2*)(xr + kh * IW);
            float2 b = *(const float2*)(xr + kh * IW + 2);
            xv[kh][0] = a.x; xv[kh][1] = a.y;
            xv[kh][2] = b.x; xv[kh][3] = b.y;
        }
        const float* wk = wlds_ + ic * 36;
#pragma unroll
        for (int kh = 0; kh < 3; kh++) {
            float wr[12];
#pragma unroll
            for (int t = 0; t < 12; t++) wr[t] = wk[kh * 12 + t];
#pragma unroll
            for (int ch = 0; ch < CPG; ch++) {
                float w0 = wr[0 * 4 + ch];
                float w1 = wr[1 * 4 + ch];
                float w2 = wr[2 * 4 + ch];
                acc[0][ch] = fmaf(xv[kh][0], w0,
                             fmaf(xv[kh][1], w1,
                             fmaf(xv[kh][2], w2, acc[0][ch])));
                acc[1][ch] = fmaf(xv[kh][1], w0,
                             fmaf(xv[kh][2], w1,
                             fmaf(xv[kh][3], w2, acc[1][ch])));
            }
        }
    }
}

// One block per (n, group), XCD-swizzled so each XCD owns contiguous images
// (verified: FETCH_SIZE 850MB -> 40MB). Single conv pass; per pool cell ONE
// 4-output-row register block (round-3 structure, 246us / VALUBusy 67%).
// Round-4 lesson: compiler unroll-2 pipelining SPILLS (WRITE_SIZE 59->235MB
// at pinned VGPR=84) -> cross-ic overlap must be a SMALL manual prefetch:
//  - nx[3][6] (18 VGPR) prefetches rows 0-2 of ic+1 before this ic's FMA
//    block; next ic's first FMA groups read ~1300-cycle-old registers instead
//    of paying the ~225cy L2 lead-in (the measured per-ic stall).
//  - rows 3-5 stay covered by the early FMA groups via compiler vmcnt waits.
// Edge strips: fine-grained edge2 (250 units, 1/thread, no wasted lanes or
// masked-out FMAs) replaces the old conv4 strips (188 threads, 50% waste).
// Weights/bias pre-multiplied by sgn(gn_w*scale): pool extreme is a bare
// fmaxf; sum/sumsq per-channel (4 parallel chains).
// out = clamp(rstd*|gn_w*scale|*M + (gn_b - mean*rstd*gn_w)*scale, 0, 1).
__launch_bounds__(256, 3)
__global__ void fused_conv_gn_pool_kernel(const float* __restrict__ x,
                                          const float* __restrict__ conv_w,
                                          const float* __restrict__ conv_b,
                                          const float* __restrict__ gn_w,
                                          const float* __restrict__ gn_b,
                                          const float* __restrict__ scale,
                                          float* __restrict__ out) {
    const int b = blockIdx.x;               // 0..2047 hardware block id
    // XCD-aware swizzle: hw blocks round-robin XCDs by (b % 8); give XCD j
    // the contiguous work range [j*256, (j+1)*256) == images j*16..j*16+15.
    const int wid = ((b & 7) << 8) | (b >> 3);
    const int n = wid >> 4;
    const int g = wid & 15;
    const int tid = threadIdx.x;

    __shared__ float wlds[IC * 3 * 3 * CPG];   // 288 floats, [ic][kh][kw][ch], signed
    __shared__ float red[8];                    // 4 waves x {sum, sumsq}
    __shared__ float stats[2];                  // mean, rstd

    for (int t = tid; t < IC * 3 * 3 * CPG; t += 256) {
        int ch = t & 3;
        int r = t >> 2;                        // ic*9 + kh*3 + kw
        int c = g * CPG + ch;
        float sg = (gn_w[c] * scale[c] >= 0.f) ? 1.f : -1.f;
        wlds[t] = conv_w[c * (IC * 9) + r] * sg;
    }
    float biasS[CPG], sgnf[CPG];
#pragma unroll
    for (int ch = 0; ch < CPG; ch++) {
        int c = g * CPG + ch;
        float sg = (gn_w[c] * scale[c] >= 0.f) ? 1.f : -1.f;
        sgnf[ch] = sg;
        biasS[ch] = conv_b[c] * sg;
    }
    __syncthreads();

    const float* xb = x + (size_t)n * (IC * IH * IW);

    float s_ch[CPG];                 // per-channel signed-conv partial sums
    float ss_ch[CPG];                // per-channel sum of squares (4 chains)
#pragma unroll
    for (int ch = 0; ch < CPG; ch++) { s_ch[ch] = 0.f; ss_ch[ch] = 0.f; }
    float pm[4][CPG];                // running extreme per owned pool cell
#pragma unroll
    for (int ci = 0; ci < 4; ci++)
#pragma unroll
        for (int ch = 0; ch < CPG; ch++) pm[ci][ch] = -INFINITY;

    // ---- Main: pool region (conv rows/cols 0..123), one pass ----
#pragma unroll 1
    for (int ci = 0; ci < 4; ci++) {
        int cell = tid + ci * 256;
        if (cell < PH * PW) {
            int ph = cell / PW;
            int pw = cell - ph * PW;
            const int r0 = 4 * ph;             // conv rows r0..r0+3
            const float* xcell = xb + r0 * IW + 4 * pw;

            float acc[4][4][CPG];              // [row][col][ch]
#pragma unroll
            for (int rr = 0; rr < 4; rr++)
#pragma unroll
                for (int j = 0; j < 4; j++)
#pragma unroll
                    for (int ch = 0; ch < CPG; ch++) acc[rr][j][ch] = biasS[ch];

            // preload rows 0-2 of ic=0 into the prefetch buffer
            float nx[3][6];
#pragma unroll
            for (int rr = 0; rr < 3; rr++) {
                float4 f4 = *(const float4*)(xcell + rr * IW);
                float2 f2 = *(const float2*)(xcell + rr * IW + 4);
                nx[rr][0] = f4.x; nx[rr][1] = f4.y;
                nx[rr][2] = f4.z; nx[rr][3] = f4.w;
                nx[rr][4] = f2.x; nx[rr][5] = f2.y;
            }

#pragma unroll 1
            for (int ic = 0; ic < IC; ic++) {
                const float* xr  = xcell + ic * (IH * IW);
                const float* xrn = xr + ((ic < IC - 1) ? (IH * IW) : 0);
                float xv[6][6];
                // rows 0-2 come from the prefetch buffer (already in flight
                // for ~1 full FMA block)
#pragma unroll
                for (int rr = 0; rr < 3; rr++)
#pragma unroll
                    for (int t = 0; t < 6; t++) xv[rr][t] = nx[rr][t];
                // rows 3-5: load now; covered by the early FMA groups that
                // only need rows 0-2 (compiler inserts partial vmcnt waits)
#pragma unroll
                for (int rr = 3; rr < 6; rr++) {
                    float4 f4 = *(const float4*)(xr + rr * IW);
                    float2 f2 = *(const float2*)(xr + rr * IW + 4);
                    xv[rr][0] = f4.x; xv[rr][1] = f4.y;
                    xv[rr][2] = f4.z; xv[rr][3] = f4.w;
                    xv[rr][4] = f2.x; xv[rr][5] = f2.y;
                }
                // prefetch rows 0-2 of NEXT ic (clamped re-load of ic=7 on
                // the last iteration: 6 L1-hot loads, avoids a branch)
#pragma unroll
                for (int rr = 0; rr < 3; rr++) {
                    float4 f4 = *(const float4*)(xrn + rr * IW);
                    float2 f2 = *(const float2*)(xrn + rr * IW + 4);
                    nx[rr][0] = f4.x; nx[rr][1] = f4.y;
                    nx[rr][2] = f4.z; nx[rr][3] = f4.w;
                    nx[rr][4] = f2.x; nx[rr][5] = f2.y;
                }
                const float* wk = wlds + ic * 36;
#pragma unroll
                for (int kh = 0; kh < 3; kh++) {
                    float wr[12];
#pragma unroll
                    for (int t = 0; t < 12; t++) wr[t] = wk[kh * 12 + t];
#pragma unroll
                    for (int ch = 0; ch < CPG; ch++) {
                        float w0 = wr[0 * 4 + ch];
                        float w1 = wr[1 * 4 + ch];
                        float w2 = wr[2 * 4 + ch];
#pragma unroll
                        for (int rr = 0; rr < 4; rr++) {
                            const float* xrow = xv[rr + kh];
#pragma unroll
                            for (int j = 0; j < 4; j++) {
                                acc[rr][j][ch] = fmaf(xrow[j],     w0,
                                                 fmaf(xrow[j + 1], w1,
                                                 fmaf(xrow[j + 2], w2, acc[rr][j][ch])));
                            }
                        }
                    }
                }
            }
            // fold into stats + pool extremes (signed domain)
#pragma unroll
            for (int rr = 0; rr < 4; rr++)
#pragma unroll
                for (int j = 0; j < 4; j++)
#pragma unroll
                    for (int ch = 0; ch < CPG; ch++) {
                        float v = acc[rr][j][ch];
                        s_ch[ch] += v;
                        ss_ch[ch] = fmaf(v, v, ss_ch[ch]);
                        pm[ci][ch] = fmaxf(pm[ci][ch], v);
                    }
        }
    }

    // ---- Edges: conv outputs needed for stats only ----
    // 250 fine-grained units, one per thread:
    //   u in [0,124): right edge, row u, cols 124-125
    //   u in [124,250): bottom rows, u2=u-124: oh=124+(u2>=63), col pair
    //   (u2 mod 63)*2 covering cols 0..125
    if (tid < 250) {
        int oh, ow;
        if (tid < 124) {
            oh = tid; ow = 124;
        } else {
            int u2 = tid - 124;
            int hi = (u2 >= 63) ? 1 : 0;
            oh = 124 + hi;
            ow = (u2 - 63 * hi) * 2;
        }
        float acc[2][CPG];
#pragma unroll
        for (int j = 0; j < 2; j++)
#pragma unroll
            for (int ch = 0; ch < CPG; ch++) acc[j][ch] = biasS[ch];
        edge2(xb, wlds, oh, ow, acc);
#pragma unroll
        for (int j = 0; j < 2; j++)
#pragma unroll
            for (int ch = 0; ch < CPG; ch++) {
                float v = acc[j][ch];
                s_ch[ch] += v;
                ss_ch[ch] = fmaf(v, v, ss_ch[ch]);
            }
    }

    // ---- Block reduction for GN stats (restore per-channel sign) ----
    float s = sgnf[0] * s_ch[0] + sgnf[1] * s_ch[1]
            + sgnf[2] * s_ch[2] + sgnf[3] * s_ch[3];
    float ss = ss_ch[0] + ss_ch[1] + ss_ch[2] + ss_ch[3];
#pragma unroll
    for (int off = 32; off > 0; off >>= 1) {
        s  += __shfl_down(s, off, 64);
        ss += __shfl_down(ss, off, 64);
    }
    int wave = tid >> 6;
    if ((tid & 63) == 0) { red[wave] = s; red[4 + wave] = ss; }
    __syncthreads();
    if (tid == 0) {
        float S  = red[0] + red[1] + red[2] + red[3];
        float SS = red[4] + red[5] + red[6] + red[7];
        const float inv_count = 1.f / (float)(CPG * OH * OW);
        float mean = S * inv_count;
        float var = SS * inv_count - mean * mean;
        if (var < 0.f) var = 0.f;
        stats[0] = mean;
        stats[1] = rsqrtf(var + GN_EPS);
    }
    __syncthreads();
    const float mean = stats[0];
    const float rstd = stats[1];

    // Fused affine for the pooled extreme: out = a2*M + b2  (a2 >= 0,
    // M is the signed-domain max, equal to max over window of sgn*v)
    float a2[CPG], b2[CPG];
#pragma unroll
    for (int ch = 0; ch < CPG; ch++) {
        int c = g * CPG + ch;
        float gw = gn_w[c], sc = scale[c];
        a2[ch] = rstd * fabsf(gw * sc);
        b2[ch] = (gn_b[c] - mean * rstd * gw) * sc;
    }

    // ---- Write pooled, clamped output ----
#pragma unroll
    for (int ci = 0; ci < 4; ci++) {
        int cell = tid + ci * 256;
        if (cell < PH * PW) {
            int ph = cell / PW;
            int pw = cell - ph * PW;
#pragma unroll
            for (int ch = 0; ch < CPG; ch++) {
                int c = g * CPG + ch;
                float v = fmaf(a2[ch], pm[ci][ch], b2[ch]);
                v = fminf(fmaxf(v, 0.f), 1.f);
                out[(((size_t)n * OC + c) * PH + ph) * PW + pw] = v;
            }
        }
    }
}

extern "C" void kernel_launch(void* const* d_in, const int* in_sizes, int n_in,
                              void* d_out, int out_size, void* d_ws, size_t ws_size,
                              hipStream_t stream) {
    const float* x      = (const float*)d_in[0];
    const float* conv_w = (const float*)d_in[1];
    const float* conv_b = (const float*)d_in[2];
    const float* gn_w   = (const float*)d_in[3];
    const float* gn_b   = (const float*)d_in[4];
    const float* scale  = (const float*)d_in[5];
    float* out = (float*)d_out;

    dim3 grid(N_IMG * NG);   // one block per (n, group), XCD-swizzled in-kernel
    dim3 block(256);
    hipLaunchKernelGGL(fused_conv_gn_pool_kernel, grid, block, 0, stream,
                       x, conv_w, conv_b, gn_w, gn_b, scale, out);
}

// Round 6
// 307.324 us; speedup vs baseline: 1.1099x; 1.0703x over previous
//
#include <hip/hip_runtime.h>
#include <math.h>

// Problem constants
#define N_IMG 128
#define IC 8
#define IH 128
#define IW 128
#define OC 64
#define OH 126
#define OW 126
#define NG 16
#define CPG 4          // channels per group
#define PH 31
#define PW 31
#define GN_EPS 1e-5f

// edge2: compute 2 consecutive output columns (ow, ow+1) x 4 channels of the
// 3x3 conv for one output row. Stats-only edge work (cols 124-125 / rows
// 124-125). ow must be even (float2 loads are 8B aligned). acc pre-init'd
// with (signed) bias. Weights in LDS [ic][kh][kw][ch], pre-multiplied by
// sgn(gn_w*scale).
__device__ __forceinline__ void edge2(const float* __restrict__ xb,
                                      const float* wlds_,
                                      int oh, int ow,
                                      float acc[2][CPG]) {
#pragma unroll 1
    for (int ic = 0; ic < IC; ic++) {
        const float* xr = xb + ic * (IH * IW) + oh * IW + ow;
        float xv[3][4];
#pragma unroll
        for (int kh = 0; kh < 3; kh++) {
            float2 a = *(const float2*)(xr + kh * IW);
            float2 b = *(const float2*)(xr + kh * IW + 2);
            xv[kh][0] = a.x; xv[kh][1] = a.y;
            xv[kh][2] = b.x; xv[kh][3] = b.y;
        }
        const float* wk = wlds_ + ic * 36;
#pragma unroll
        for (int kh = 0; kh < 3; kh++) {
            float wr[12];
#pragma unroll
            for (int t = 0; t < 12; t++) wr[t] = wk[kh * 12 + t];
#pragma unroll
            for (int ch = 0; ch < CPG; ch++) {
                float w0 = wr[0 * 4 + ch];
                float w1 = wr[1 * 4 + ch];
                float w2 = wr[2 * 4 + ch];
                acc[0][ch] = fmaf(xv[kh][0], w0,
                             fmaf(xv[kh][1], w1,
                             fmaf(xv[kh][2], w2, acc[0][ch])));
                acc[1][ch] = fmaf(xv[kh][1], w0,
                             fmaf(xv[kh][2], w1,
                             fmaf(xv[kh][3], w2, acc[1][ch])));
            }
        }
    }
}

// One block per (n, group), XCD-swizzled so each XCD owns contiguous images
// (verified: FETCH_SIZE 850MB -> 40MB). Single conv pass; per pool cell ONE
// 4-output-row register block + nx[3][6] manual cross-ic prefetch of rows 0-2
// (next ic's first FMA groups read registers in flight for a full FMA block
// instead of paying the ~225cy lead-in).
//
// REGISTER-BUDGET FIX (round-5 lesson): VGPR_Count pinned at 84 = 512/6
// across rounds 3-5 -- the allocator holds a 6-waves/EU budget and SPILLS
// (WRITE_SIZE 59->209MB) rather than exceed it, even though achieved
// occupancy is only ~2.4 waves/SIMD. amdgpu_waves_per_eu(2,4) widens the
// budget to 256 VGPR (min 2 waves/EU) so the prefetch lives in registers.
//
// Edge strips: fine-grained edge2 (250 units, 1/thread, no wasted lanes).
// Weights/bias pre-multiplied by sgn(gn_w*scale): pool extreme is a bare
// fmaxf; sum/sumsq per-channel (4 parallel chains).
// out = clamp(rstd*|gn_w*scale|*M + (gn_b - mean*rstd*gn_w)*scale, 0, 1).
__attribute__((amdgpu_waves_per_eu(2, 4)))
__launch_bounds__(256)
__global__ void fused_conv_gn_pool_kernel(const float* __restrict__ x,
                                          const float* __restrict__ conv_w,
                                          const float* __restrict__ conv_b,
                                          const float* __restrict__ gn_w,
                                          const float* __restrict__ gn_b,
                                          const float* __restrict__ scale,
                                          float* __restrict__ out) {
    const int b = blockIdx.x;               // 0..2047 hardware block id
    // XCD-aware swizzle: hw blocks round-robin XCDs by (b % 8); give XCD j
    // the contiguous work range [j*256, (j+1)*256) == images j*16..j*16+15.
    const int wid = ((b & 7) << 8) | (b >> 3);
    const int n = wid >> 4;
    const int g = wid & 15;
    const int tid = threadIdx.x;

    __shared__ float wlds[IC * 3 * 3 * CPG];   // 288 floats, [ic][kh][kw][ch], signed
    __shared__ float red[8];                    // 4 waves x {sum, sumsq}
    __shared__ float stats[2];                  // mean, rstd

    for (int t = tid; t < IC * 3 * 3 * CPG; t += 256) {
        int ch = t & 3;
        int r = t >> 2;                        // ic*9 + kh*3 + kw
        int c = g * CPG + ch;
        float sg = (gn_w[c] * scale[c] >= 0.f) ? 1.f : -1.f;
        wlds[t] = conv_w[c * (IC * 9) + r] * sg;
    }
    float biasS[CPG], sgnf[CPG];
#pragma unroll
    for (int ch = 0; ch < CPG; ch++) {
        int c = g * CPG + ch;
        float sg = (gn_w[c] * scale[c] >= 0.f) ? 1.f : -1.f;
        sgnf[ch] = sg;
        biasS[ch] = conv_b[c] * sg;
    }
    __syncthreads();

    const float* xb = x + (size_t)n * (IC * IH * IW);

    float s_ch[CPG];                 // per-channel signed-conv partial sums
    float ss_ch[CPG];                // per-channel sum of squares (4 chains)
#pragma unroll
    for (int ch = 0; ch < CPG; ch++) { s_ch[ch] = 0.f; ss_ch[ch] = 0.f; }
    float pm[4][CPG];                // running extreme per owned pool cell
#pragma unroll
    for (int ci = 0; ci < 4; ci++)
#pragma unroll
        for (int ch = 0; ch < CPG; ch++) pm[ci][ch] = -INFINITY;

    // ---- Main: pool region (conv rows/cols 0..123), one pass ----
#pragma unroll 1
    for (int ci = 0; ci < 4; ci++) {
        int cell = tid + ci * 256;
        if (cell < PH * PW) {
            int ph = cell / PW;
            int pw = cell - ph * PW;
            const int r0 = 4 * ph;             // conv rows r0..r0+3
            const float* xcell = xb + r0 * IW + 4 * pw;

            float acc[4][4][CPG];              // [row][col][ch]
#pragma unroll
            for (int rr = 0; rr < 4; rr++)
#pragma unroll
                for (int j = 0; j < 4; j++)
#pragma unroll
                    for (int ch = 0; ch < CPG; ch++) acc[rr][j][ch] = biasS[ch];

            // preload rows 0-2 of ic=0 into the prefetch buffer
            float nx[3][6];
#pragma unroll
            for (int rr = 0; rr < 3; rr++) {
                float4 f4 = *(const float4*)(xcell + rr * IW);
                float2 f2 = *(const float2*)(xcell + rr * IW + 4);
                nx[rr][0] = f4.x; nx[rr][1] = f4.y;
                nx[rr][2] = f4.z; nx[rr][3] = f4.w;
                nx[rr][4] = f2.x; nx[rr][5] = f2.y;
            }

#pragma unroll 1
            for (int ic = 0; ic < IC; ic++) {
                const float* xr  = xcell + ic * (IH * IW);
                const float* xrn = xr + ((ic < IC - 1) ? (IH * IW) : 0);
                float xv[6][6];
                // rows 0-2 come from the prefetch buffer (already in flight
                // for ~1 full FMA block)
#pragma unroll
                for (int rr = 0; rr < 3; rr++)
#pragma unroll
                    for (int t = 0; t < 6; t++) xv[rr][t] = nx[rr][t];
                // rows 3-5: load now; covered by the early FMA groups that
                // only need rows 0-2 (compiler inserts partial vmcnt waits)
#pragma unroll
                for (int rr = 3; rr < 6; rr++) {
                    float4 f4 = *(const float4*)(xr + rr * IW);
                    float2 f2 = *(const float2*)(xr + rr * IW + 4);
                    xv[rr][0] = f4.x; xv[rr][1] = f4.y;
                    xv[rr][2] = f4.z; xv[rr][3] = f4.w;
                    xv[rr][4] = f2.x; xv[rr][5] = f2.y;
                }
                // prefetch rows 0-2 of NEXT ic (clamped re-load of ic=7 on
                // the last iteration: 6 L1-hot loads, avoids a branch)
#pragma unroll
                for (int rr = 0; rr < 3; rr++) {
                    float4 f4 = *(const float4*)(xrn + rr * IW);
                    float2 f2 = *(const float2*)(xrn + rr * IW + 4);
                    nx[rr][0] = f4.x; nx[rr][1] = f4.y;
                    nx[rr][2] = f4.z; nx[rr][3] = f4.w;
                    nx[rr][4] = f2.x; nx[rr][5] = f2.y;
                }
                const float* wk = wlds + ic * 36;
#pragma unroll
                for (int kh = 0; kh < 3; kh++) {
                    float wr[12];
#pragma unroll
                    for (int t = 0; t < 12; t++) wr[t] = wk[kh * 12 + t];
#pragma unroll
                    for (int ch = 0; ch < CPG; ch++) {
                        float w0 = wr[0 * 4 + ch];
                        float w1 = wr[1 * 4 + ch];
                        float w2 = wr[2 * 4 + ch];
#pragma unroll
                        for (int rr = 0; rr < 4; rr++) {
                            const float* xrow = xv[rr + kh];
#pragma unroll
                            for (int j = 0; j < 4; j++) {
                                acc[rr][j][ch] = fmaf(xrow[j],     w0,
                                                 fmaf(xrow[j + 1], w1,
                                                 fmaf(xrow[j + 2], w2, acc[rr][j][ch])));
                            }
                        }
                    }
                }
            }
            // fold into stats + pool extremes (signed domain)
#pragma unroll
            for (int rr = 0; rr < 4; rr++)
#pragma unroll
                for (int j = 0; j < 4; j++)
#pragma unroll
                    for (int ch = 0; ch < CPG; ch++) {
                        float v = acc[rr][j][ch];
                        s_ch[ch] += v;
                        ss_ch[ch] = fmaf(v, v, ss_ch[ch]);
                        pm[ci][ch] = fmaxf(pm[ci][ch], v);
                    }
        }
    }

    // ---- Edges: conv outputs needed for stats only ----
    // 250 fine-grained units, one per thread:
    //   u in [0,124): right edge, row u, cols 124-125
    //   u in [124,250): bottom rows, u2=u-124: oh=124+(u2>=63), col pair
    //   (u2 mod 63)*2 covering cols 0..125
    if (tid < 250) {
        int oh, ow;
        if (tid < 124) {
            oh = tid; ow = 124;
        } else {
            int u2 = tid - 124;
            int hi = (u2 >= 63) ? 1 : 0;
            oh = 124 + hi;
            ow = (u2 - 63 * hi) * 2;
        }
        float acc[2][CPG];
#pragma unroll
        for (int j = 0; j < 2; j++)
#pragma unroll
            for (int ch = 0; ch < CPG; ch++) acc[j][ch] = biasS[ch];
        edge2(xb, wlds, oh, ow, acc);
#pragma unroll
        for (int j = 0; j < 2; j++)
#pragma unroll
            for (int ch = 0; ch < CPG; ch++) {
                float v = acc[j][ch];
                s_ch[ch] += v;
                ss_ch[ch] = fmaf(v, v, ss_ch[ch]);
            }
    }

    // ---- Block reduction for GN stats (restore per-channel sign) ----
    float s = sgnf[0] * s_ch[0] + sgnf[1] * s_ch[1]
            + sgnf[2] * s_ch[2] + sgnf[3] * s_ch[3];
    float ss = ss_ch[0] + ss_ch[1] + ss_ch[2] + ss_ch[3];
#pragma unroll
    for (int off = 32; off > 0; off >>= 1) {
        s  += __shfl_down(s, off, 64);
        ss += __shfl_down(ss, off, 64);
    }
    int wave = tid >> 6;
    if ((tid & 63) == 0) { red[wave] = s; red[4 + wave] = ss; }
    __syncthreads();
    if (tid == 0) {
        float S  = red[0] + red[1] + red[2] + red[3];
        float SS = red[4] + red[5] + red[6] + red[7];
        const float inv_count = 1.f / (float)(CPG * OH * OW);
        float mean = S * inv_count;
        float var = SS * inv_count - mean * mean;
        if (var < 0.f) var = 0.f;
        stats[0] = mean;
        stats[1] = rsqrtf(var + GN_EPS);
    }
    __syncthreads();
    const float mean = stats[0];
    const float rstd = stats[1];

    // Fused affine for the pooled extreme: out = a2*M + b2  (a2 >= 0,
    // M is the signed-domain max, equal to max over window of sgn*v)
    float a2[CPG], b2[CPG];
#pragma unroll
    for (int ch = 0; ch < CPG; ch++) {
        int c = g * CPG + ch;
        float gw = gn_w[c], sc = scale[c];
        a2[ch] = rstd * fabsf(gw * sc);
        b2[ch] = (gn_b[c] - mean * rstd * gw) * sc;
    }

    // ---- Write pooled, clamped output ----
#pragma unroll
    for (int ci = 0; ci < 4; ci++) {
        int cell = tid + ci * 256;
        if (cell < PH * PW) {
            int ph = cell / PW;
            int pw = cell - ph * PW;
#pragma unroll
            for (int ch = 0; ch < CPG; ch++) {
                int c = g * CPG + ch;
                float v = fmaf(a2[ch], pm[ci][ch], b2[ch]);
                v = fminf(fmaxf(v, 0.f), 1.f);
                out[(((size_t)n * OC + c) * PH + ph) * PW + pw] = v;
            }
        }
    }
}

extern "C" void kernel_launch(void* const* d_in, const int* in_sizes, int n_in,
                              void* d_out, int out_size, void* d_ws, size_t ws_size,
                              hipStream_t stream) {
    const float* x      = (const float*)d_in[0];
    const float* conv_w = (const float*)d_in[1];
    const float* conv_b = (const float*)d_in[2];
    const float* gn_w   = (const float*)d_in[3];
    const float* gn_b   = (const float*)d_in[4];
    const float* scale  = (const float*)d_in[5];
    float* out = (float*)d_out;

    dim3 grid(N_IMG * NG);   // one block per (n, group), XCD-swizzled in-kernel
    dim3 block(256);
    hipLaunchKernelGGL(fused_conv_gn_pool_kernel, grid, block, 0, stream,
                       x, conv_w, conv_b, gn_w, gn_b, scale, out);
}